// Round 8
// baseline (333.604 us; speedup 1.0000x reference)
//
#include <hip/hip_runtime.h>
#include <stdint.h>

// Problem constants (from reference setup_inputs)
#define M_TOK 8192
#define N_OUT 4096
#define K_IN  4096

// GEMM tiling: 256x128 tile, BK=32, 3-buffer LDS ring (72 KiB), 4 waves 2x2.
// 2 blocks/CU (the point of this round): blocks drift independently, so one
// block's DS window overlaps the other's MFMA window (m114 mechanism).
#define BM 256
#define BN 128
#define BK 32
#define NT (K_IN / BK)            // 128 K-steps
#define BUFS 12288                // shorts per ring buffer (24 KiB): A 8192 | B 4096
#define BOFF 8192                 // B section offset (shorts)

typedef float floatx4 __attribute__((ext_vector_type(4)));
typedef __bf16 bf16x8 __attribute__((ext_vector_type(8)));
typedef unsigned short ushort8_t __attribute__((ext_vector_type(8)));

#define MFMA16 __builtin_amdgcn_mfma_f32_16x16x32_bf16

// ---------- helpers ----------

__device__ __forceinline__ unsigned short f32_to_bf16_rne(float f) {
    union { float f; unsigned int u; } v; v.f = f;
    unsigned int u = v.u;
    u += 0x7FFFu + ((u >> 16) & 1u);   // round-to-nearest-even; inputs have no NaN
    return (unsigned short)(u >> 16);
}

// async global->LDS, 16 bytes per lane. LDS side is wave-uniform base + lane*16.
__device__ __forceinline__ void async_copy16(const void* g, void* l) {
    __builtin_amdgcn_global_load_lds(
        (__attribute__((address_space(1))) void*)(g),
        (__attribute__((address_space(3))) void*)(l),
        16, 0, 0);
}

// ---------- pre-pass: fp32 -> bf16 ----------

__global__ void cvt_f32_bf16_kernel(const float* __restrict__ in,
                                    unsigned short* __restrict__ out, int n8) {
    int i = blockIdx.x * 256 + threadIdx.x;
    if (i >= n8) return;
    const float4* p = (const float4*)in + (size_t)i * 2;
    float4 a = p[0];
    float4 b = p[1];
    ushort8_t o;
    o[0] = f32_to_bf16_rne(a.x); o[1] = f32_to_bf16_rne(a.y);
    o[2] = f32_to_bf16_rne(a.z); o[3] = f32_to_bf16_rne(a.w);
    o[4] = f32_to_bf16_rne(b.x); o[5] = f32_to_bf16_rne(b.y);
    o[6] = f32_to_bf16_rne(b.z); o[7] = f32_to_bf16_rne(b.w);
    *((ushort8_t*)out + i) = o;
}

// ---------- pre-pass: int32 (int8-valued) -> bf16 (exact) ----------

__global__ void cvt_i32_bf16_kernel(const int* __restrict__ in,
                                    unsigned short* __restrict__ out, int n8) {
    int i = blockIdx.x * 256 + threadIdx.x;
    if (i >= n8) return;
    const int4* p = (const int4*)in + (size_t)i * 2;
    int4 a = p[0];
    int4 b = p[1];
    ushort8_t o;
    o[0] = f32_to_bf16_rne((float)a.x); o[1] = f32_to_bf16_rne((float)a.y);
    o[2] = f32_to_bf16_rne((float)a.z); o[3] = f32_to_bf16_rne((float)a.w);
    o[4] = f32_to_bf16_rne((float)b.x); o[5] = f32_to_bf16_rne((float)b.y);
    o[6] = f32_to_bf16_rne((float)b.z); o[7] = f32_to_bf16_rne((float)b.w);
    *((ushort8_t*)out + i) = o;
}

// ---------- GEMM: C[m][n] = sum_k A[m][k]*B[n][k]; C = acc*scale[n]+bias[n] ----------
// LOCKSTEP BREAKER: R4/R6/R7 all tied at ~247us / MfmaUtil ~50% because the
// single 8-wave block barrier-locks the whole CU into alternating DS/MFMA
// windows (measured: tile time = MFMA work + DS work, zero overlap). This
// version runs 2 INDEPENDENT 4-wave blocks per CU (72 KiB LDS each); their
// phases drift, so block A's DS window runs under block B's MFMA window.
//
// Per K-step (BK=32) per block: one vmcnt(0) (drains 6 stage loads issued a
// full step earlier - old, cheap) + one barrier (publishes buf(t+1)), stage
// t+2 into ring slot (6 global_load_lds), read frags(t+1) into the alternate
// register set (12 ds_read_b128), counted lgkmcnt(12) (drains step-t reads
// only), 32 MFMA on the current set.
//
// Hazards (airtight): (a) stage(t+2) -> buf[(t+2)%3] issues AFTER barrier(t);
// its previous readers (frags(t-1)) were lgkm-drained by each wave in step
// t-1 before that wave reached barrier(t). (b) reads(t+1) happen after
// barrier(t); every wave executed vmcnt(0) (draining ALL stage(t+1) loads)
// before barrier(t). (c) MFMA(t) operands drained by this step's lgkmcnt(12).
//
// LDS: per ring buffer, A[256 rows][32] | B[128 rows][32], PAIR-ROW swizzle
// (R3/R4-verified 0 conflicts; BK=32 rows are the same 32-short geometry):
// pair p = row>>1 (128 B) holds rows {2p,2p+1}; chunk (p,c) holds
// (row = 2p+(cg>>2), kchunk = cg&3), cg = c ^ (p&7); inverse applied on the
// per-lane GLOBAL source, linear LDS dest. Every ds_read_b128 covers one
// contiguous 1 KiB window exactly once (the R5 lesson).

__global__ __launch_bounds__(256, 2)
void gemm_bf16_kernel(const unsigned short* __restrict__ A,
                      const unsigned short* __restrict__ B,
                      const float* __restrict__ scales,
                      const float* __restrict__ bias,
                      float* __restrict__ C) {
    __shared__ __align__(16) unsigned short lds[3 * BUFS];   // 72 KiB

    const int tid = threadIdx.x;

    // T1: bijective XCD swizzle (nwg = 1024, divisible by 8), bn-fastest.
    const int nwg = (M_TOK / BM) * (N_OUT / BN);   // 32*32 = 1024
    const int cpx = nwg / 8;                        // 128
    const int wg  = (blockIdx.x % 8) * cpx + blockIdx.x / 8;
    const int bn  = wg & 31;                        // N_OUT/BN = 32
    const int bm  = wg >> 5;                        // 0..31

    const int lane = tid & 63;
    const int wave = tid >> 6;          // 0..3
    const int wm   = wave >> 1;         // 0..1 -> rows wm*128
    const int wn   = wave & 1;          // 0..1 -> cols wn*64

    // ---- staging addressing (loop-invariant; pair-row inverse swizzle) ----
    // One issue = 256 lanes x 16 B = 4 KiB = 32 pairs = 64 rows.
    const int t8 = tid >> 3;                        // 0..31 (pair within issue)
    const int cg = (tid & 7) ^ (t8 & 7);            // unswizzled chunk in pair
    const int grow0 = 2 * t8 + (cg >> 2);           // row within 64-row issue
    const int gcol0 = (cg & 3) * 8;                 // shorts within k-slice
    const unsigned short* aP = A + (size_t)(bm * BM + grow0) * K_IN + gcol0;
    const unsigned short* bP = B + (size_t)(bn * BN + grow0) * K_IN + gcol0;

    auto stage = [&](unsigned short* d, int tt) {
        const unsigned short* ga = aP + tt * BK;
#pragma unroll
        for (int i = 0; i < 4; ++i)                 // A: 256 rows = 4 issues
            async_copy16(ga + (size_t)i * 64 * K_IN, d + i * 2048 + tid * 8);
        const unsigned short* gb = bP + tt * BK;
#pragma unroll
        for (int i = 0; i < 2; ++i)                 // B: 128 rows = 2 issues
            async_copy16(gb + (size_t)i * 64 * K_IN, d + BOFF + i * 2048 + tid * 8);
    };

    // ---- fragment read addressing (loop-invariant) ----
    // Frag row R: pair p = R>>1, c = ((R&1)*4 + q) ^ ((R>>1)&7).
    const int r16 = lane & 15;
    const int q   = lane >> 4;                      // 0..3
    const int cr  = (((r16 & 1) << 2) + q) ^ ((r16 >> 1) & 7);
    const int aOff = (wm * 64 + (r16 >> 1)) * 64 + cr * 8;
    const int bOff = BOFF + (wn * 32 + (r16 >> 1)) * 64 + cr * 8;

    floatx4 acc[8][4] = {};
    bf16x8 afX[8], afY[8], bfX[4], bfY[4];

    auto rdAB = [&](bf16x8 (&af)[8], bf16x8 (&bf)[4], const unsigned short* base) {
#pragma unroll
        for (int i = 0; i < 8; ++i) af[i] = *(const bf16x8*)(base + aOff + i * 512);
#pragma unroll
        for (int j = 0; j < 4; ++j) bf[j] = *(const bf16x8*)(base + bOff + j * 512);
    };
    auto mmall = [&](bf16x8 (&af)[8], bf16x8 (&bf)[4]) {
        __builtin_amdgcn_s_setprio(1);
#pragma unroll
        for (int i = 0; i < 8; ++i)
#pragma unroll
            for (int j = 0; j < 4; ++j)
                acc[i][j] = MFMA16(af[i], bf[j], acc[i][j], 0, 0, 0);
        __builtin_amdgcn_s_setprio(0);
    };

    unsigned short* r0 = lds;               // ring: buf(t)
    unsigned short* r1 = lds + BUFS;        // buf(t+1)
    unsigned short* r2 = lds + 2 * BUFS;    // buf(t+2)

    // ---- prologue: stage 0 and 1, publish 0, read frags(0) -> X ----
    stage(r0, 0);
    stage(r1, 1);
    asm volatile("s_waitcnt vmcnt(6)" ::: "memory");   // stage(0) landed
    __builtin_amdgcn_s_barrier();
    asm volatile("" ::: "memory");
    rdAB(afX, bfX, r0);                                // 12 reads in flight

    auto step = [&](int T, bf16x8 (&afC)[8], bf16x8 (&bfC)[4],
                    bf16x8 (&afN)[8], bf16x8 (&bfN)[4],
                    const unsigned short* pnext, unsigned short* pstage) {
        asm volatile("s_waitcnt vmcnt(0)" ::: "memory");  // drain stage(T+1), old
        __builtin_amdgcn_s_barrier();                     // publish buf(T+1)
        asm volatile("" ::: "memory");
        if (T + 2 < NT) stage(pstage, T + 2);
        if (T + 1 < NT) {
            rdAB(afN, bfN, pnext);                        // 12 reads for T+1
            asm volatile("s_waitcnt lgkmcnt(12)" ::: "memory");  // drain T's reads
        } else {
            asm volatile("s_waitcnt lgkmcnt(0)" ::: "memory");
        }
        __builtin_amdgcn_sched_barrier(0);
        mmall(afC, bfC);                                  // 32 MFMA on T's frags
    };

#pragma unroll 1
    for (int t = 0; t < NT; t += 2) {
        step(t,     afX, bfX, afY, bfY, r1, r2);
        step(t + 1, afY, bfY, afX, bfX, r2, r0);
        unsigned short* tmp = r0; r0 = r2; r2 = r1; r1 = tmp;  // advance ring by 2
    }

    // ---- epilogue: C/D layout col = lane&15, row = (lane>>4)*4 + reg ----
    const int row0 = bm * BM + wm * 128 + q * 4;
    const int col0 = bn * BN + wn * 64 + r16;
#pragma unroll
    for (int fc = 0; fc < 4; ++fc) {
        const int n  = col0 + fc * 16;
        const float sc = scales[n];
        const float bi = bias[n];
#pragma unroll
        for (int fr = 0; fr < 8; ++fr) {
            const int m = row0 + fr * 16;
#pragma unroll
            for (int r = 0; r < 4; ++r)
                C[(size_t)(m + r) * N_OUT + n] = acc[fr][fc][r] * sc + bi;
        }
    }
}

// ---------- launch ----------

extern "C" void kernel_launch(void* const* d_in, const int* in_sizes, int n_in,
                              void* d_out, int out_size, void* d_ws, size_t ws_size,
                              hipStream_t stream) {
    const float* x      = (const float*)d_in[0];
    const int*   wq     = (const int*)d_in[1];
    const float* scales = (const float*)d_in[2];
    const float* bias   = (const float*)d_in[3];
    float*       out    = (float*)d_out;

    unsigned short* xb = (unsigned short*)d_ws;                       // 64 MiB
    unsigned short* wb = xb + (size_t)M_TOK * K_IN;                   // 32 MiB
    // ws needed: (8192*4096 + 4096*4096) * 2 = 96 MiB

    const int nx8 = (M_TOK * K_IN) / 8;   // 4194304
    const int nw8 = (N_OUT * K_IN) / 8;   // 2097152
    cvt_f32_bf16_kernel<<<nx8 / 256, 256, 0, stream>>>(x, xb, nx8);
    cvt_i32_bf16_kernel<<<nw8 / 256, 256, 0, stream>>>(wq, wb, nw8);

    const int grid = (M_TOK / BM) * (N_OUT / BN);   // 32 * 32 = 1024
    gemm_bf16_kernel<<<grid, 256, 0, stream>>>(xb, wb, scales, bias, out);
}